// Round 7
// baseline (175.217 us; speedup 1.0000x reference)
//
#include <hip/hip_runtime.h>
#include <math.h>

#define CCH 512
#define SSQ 2048           // M*T
#define MTOT 4096          // B*S rows

typedef __bf16 bf16;
typedef __bf16 bf16x8 __attribute__((ext_vector_type(8)));
typedef __bf16 bf16x4 __attribute__((ext_vector_type(4)));
typedef float  f32x4  __attribute__((ext_vector_type(4)));

#define AS1 __attribute__((address_space(1)))
#define AS3 __attribute__((address_space(3)))
__device__ __forceinline__ void glds16(const void* g, void* l) {
    __builtin_amdgcn_global_load_lds((const AS1 void*)g, (AS3 void*)l, 16, 0, 0);
}

// ---------------- fused GN-stats (blocks 0..255) + weight transpose (blocks 256..575)
__global__ __launch_bounds__(256) void gnw_kernel(const float* __restrict__ x,
        float* __restrict__ mu, float* __restrict__ rstd,
        const float* __restrict__ w0, const float* __restrict__ w1,
        const float* __restrict__ w2, const float* __restrict__ w3,
        const float* __restrict__ w4, bf16* __restrict__ wT) {
    __shared__ float smem[64*65];
    int tid = threadIdx.x;
    if (blockIdx.x < 256) {
        float* s_sum = smem;
        float* s_sq  = smem + 256;
        int bg = blockIdx.x;
        long base = (long)bg * 8192;
        float sum = 0.f, sq = 0.f;
#pragma unroll
        for (int r = 0; r < 32; ++r) {
            float v = x[base + r*256 + tid];
            sum += v; sq += v*v;
        }
        s_sum[tid] = sum; s_sq[tid] = sq;
        __syncthreads();
        for (int off = 128; off > 0; off >>= 1) {
            if (tid < off) { s_sum[tid] += s_sum[tid+off]; s_sq[tid] += s_sq[tid+off]; }
            __syncthreads();
        }
        if (tid == 0) {
            float m = s_sum[0] * (1.f/8192.f);
            float v = s_sq[0]  * (1.f/8192.f) - m*m;
            mu[bg] = m;
            rstd[bg] = rsqrtf(v + 1e-5f);
        }
    } else {
        int bid = blockIdx.x - 256;
        int z = bid >> 6, r2 = bid & 63;
        int k0 = (r2 >> 3)*64, n0 = (r2 & 7)*64;
        const float* srcs[5] = {w0, w1, w2, w3, w4};
        const float* W = srcs[z];
        bf16* D = wT + (long)z * (CCH*CCH);
        float (*t)[65] = (float(*)[65])smem;
        int cI = tid & 63, r4 = tid >> 6;
#pragma unroll
        for (int p = 0; p < 16; ++p) {
            int kr = p*4 + r4;
            t[kr][cI] = W[(long)(k0+kr)*CCH + n0 + cI];
        }
        __syncthreads();
#pragma unroll
        for (int p = 0; p < 16; ++p) {
            int nr = p*4 + r4;
            D[(long)(n0+nr)*CCH + k0 + cI] = (bf16)t[cI][nr];
        }
    }
}

// ---------------- transpose+norm: x (B,C,S) fp32 -> xnT (B,S,C) bf16
__global__ void tn_kernel(const float* __restrict__ x, const float* __restrict__ mu,
                          const float* __restrict__ rstd, const float* __restrict__ gsc,
                          const float* __restrict__ gbs, bf16* __restrict__ xnT) {
    __shared__ float t[64][65];
    int s0 = blockIdx.x*64, c0 = blockIdx.y*64, b = blockIdx.z;
    int tid = threadIdx.x;
    int cI = tid & 63, r4 = tid >> 6;
#pragma unroll
    for (int p = 0; p < 16; ++p) {
        int cr = p*4 + r4;
        t[cr][cI] = x[((long)(b*CCH + c0 + cr))*SSQ + s0 + cI];
    }
    __syncthreads();
#pragma unroll
    for (int p = 0; p < 16; ++p) {
        int sr = p*4 + r4;
        int c = c0 + cI;
        int g = b*128 + (c >> 2);
        float v = (t[cI][sr] - mu[g]) * rstd[g] * gsc[c] + gbs[c];
        xnT[((long)(b*SSQ + s0 + sr))*CCH + c] = (bf16)v;
    }
}

// ---------------- fused depthwise 3x3 (SAME) q/k/v on (B,S,C) bf16
__global__ __launch_bounds__(256) void dw3_kernel(const bf16* __restrict__ xnT,
        const float* __restrict__ dwq, const float* __restrict__ dwk,
        const float* __restrict__ dwv,
        bf16* __restrict__ yq, bf16* __restrict__ yk, bf16* __restrict__ yv) {
    int tid = threadIdx.x;
    int cc = (tid & 63) * 8;
    int s  = blockIdx.x*4 + (tid >> 6);
    int sl = s & (SSQ-1);
    int b  = s >> 11;
    int m = sl >> 7, t = sl & 127;
    float aq[8] = {}, ak[8] = {}, av[8] = {};
#pragma unroll
    for (int di = 0; di < 3; ++di) {
        int m2 = m + di - 1;
        if ((unsigned)m2 >= 16u) continue;
#pragma unroll
        for (int dj = 0; dj < 3; ++dj) {
            int t2 = t + dj - 1;
            if ((unsigned)t2 >= 128u) continue;
            bf16x8 xv = *(const bf16x8*)(xnT + ((long)(b*SSQ + m2*128 + t2))*CCH + cc);
            int wi = (di*3 + dj)*CCH + cc;
#pragma unroll
            for (int i = 0; i < 8; ++i) {
                float xf = (float)xv[i];
                aq[i] += xf * dwq[wi+i];
                ak[i] += xf * dwk[wi+i];
                av[i] += xf * dwv[wi+i];
            }
        }
    }
    bf16x8 oq, ok, ov;
#pragma unroll
    for (int i = 0; i < 8; ++i) { oq[i] = (bf16)aq[i]; ok[i] = (bf16)ak[i]; ov[i] = (bf16)av[i]; }
    long o = (long)s*CCH + cc;
    *(bf16x8*)(yq + o) = oq;
    *(bf16x8*)(yk + o) = ok;
    *(bf16x8*)(yv + o) = ov;
}

// ---------------- GEMM core v3: 128x64 tile, BK=64, glds16 double-buffer,
// ONE barrier per K-iter. 4 waves (2m x 2n), wave = 64m x 32n, 16 MFMA/iter.
// LDS: As[2] 16KB + Bs[2] 8KB = 48KB.
__device__ __forceinline__ void gemm_core(const bf16* __restrict__ A,
        const bf16* __restrict__ Wt, int m0, int n0,
        char* As0, char* Bs0, f32x4 acc[4][2]) {
    int tid = threadIdx.x, lane = tid & 63, wid = tid >> 6;
    int sw = wid & 1, nw = wid >> 1;
    int col = lane & 15, quad = lane >> 4;
    const char* gA[4]; int loA[4];
#pragma unroll
    for (int p = 0; p < 4; ++p) {
        int idx = tid + p*256;
        int row = idx >> 3;
        int c = (idx & 7) ^ (row & 7);
        gA[p] = (const char*)A + ((long)(m0+row)*CCH + c*8)*2;
        loA[p] = idx*16;
    }
    const char* gB[2]; int loB[2];
#pragma unroll
    for (int p = 0; p < 2; ++p) {
        int idx = tid + p*256;
        int row = idx >> 3;
        int c = (idx & 7) ^ (row & 7);
        gB[p] = (const char*)Wt + ((long)(n0+row)*CCH + c*8)*2;
        loB[p] = idx*16;
    }
    int rowA = sw*64 + col, rowB = nw*32 + col;
    // prologue: stage k0=0 into buf0
#pragma unroll
    for (int p = 0; p < 4; ++p) glds16(gA[p], As0 + loA[p]);
#pragma unroll
    for (int p = 0; p < 2; ++p) glds16(gB[p], Bs0 + loB[p]);
#pragma unroll
    for (int it = 0; it < 8; ++it) {
        __syncthreads();                       // drains glds for buf[it&1]
        if (it < 7) {                          // stage next into other buffer
            int k2 = (it+1)*128;               // byte offset of next k-slice
            char* An = As0 + ((it+1)&1)*16384;
            char* Bn = Bs0 + ((it+1)&1)*8192;
#pragma unroll
            for (int p = 0; p < 4; ++p) glds16(gA[p] + k2, An + loA[p]);
#pragma unroll
            for (int p = 0; p < 2; ++p) glds16(gB[p] + k2, Bn + loB[p]);
        }
        const char* Ab = As0 + (it&1)*16384;
        const char* Bb = Bs0 + (it&1)*8192;
        bf16x8 af[4][2], bfr[2][2];
#pragma unroll
        for (int mt = 0; mt < 4; ++mt) {
            int r = rowA + mt*16;
#pragma unroll
            for (int ks = 0; ks < 2; ++ks) {
                int c = (ks*4 + quad) ^ (r & 7);
                af[mt][ks] = *(const bf16x8*)(Ab + r*128 + c*16);
            }
        }
#pragma unroll
        for (int nt = 0; nt < 2; ++nt) {
            int r = rowB + nt*16;
#pragma unroll
            for (int ks = 0; ks < 2; ++ks) {
                int c = (ks*4 + quad) ^ (r & 7);
                bfr[nt][ks] = *(const bf16x8*)(Bb + r*128 + c*16);
            }
        }
#pragma unroll
        for (int ks = 0; ks < 2; ++ks)
#pragma unroll
            for (int mt = 0; mt < 4; ++mt)
#pragma unroll
                for (int nt = 0; nt < 2; ++nt)
                    acc[mt][nt] = __builtin_amdgcn_mfma_f32_16x16x32_bf16(
                        af[mt][ks], bfr[nt][ks], acc[mt][nt], 0,0,0);
    }
}

// ---------------- fused QKV GEMM: z selects matrix + epilogue
__global__ __launch_bounds__(256) void gemm_qkv(const bf16* __restrict__ Abase,
        const bf16* __restrict__ wT, bf16* __restrict__ qout,
        bf16* __restrict__ kout, bf16* __restrict__ vout) {
    __shared__ char As[2*16384];
    __shared__ char Bs[2*8192];
    int m0 = blockIdx.x*128, n0 = blockIdx.y*64, z = blockIdx.z;
    f32x4 acc[4][2] = {};
    gemm_core(Abase + (long)z*MTOT*CCH, wT + (long)z*CCH*CCH, m0, n0, As, Bs, acc);
    int tid = threadIdx.x, lane = tid & 63, wid = tid >> 6;
    int sw = wid & 1, nw = wid >> 1;
    int col = lane & 15, quad = lane >> 4;
    int nb = n0 + nw*32, mb = m0 + sw*64;
    if (z < 2) {
        bf16* outp = z ? kout : qout;
        float invf = __expf(-(float)col * 0.5756462732485114f);  // 10000^(-col/16)
        bool tHalf = (nb & 32) != 0;
        const float sc = z ? 1.0f : 0.125f;
#pragma unroll
        for (int mt = 0; mt < 4; ++mt)
#pragma unroll
            for (int r = 0; r < 4; ++r) {
                int row = mb + mt*16 + quad*4 + r;
                int sl = row & (SSQ-1);
                float pos = tHalf ? (float)(sl & 127) : (float)(sl >> 7);
                float ang = pos * invf;
                float sn, cs;
                __sincosf(ang, &sn, &cs);
                float x1 = acc[mt][0][r], x2 = acc[mt][1][r];
                outp[(long)row*CCH + nb + col]      = (bf16)((x1*cs - x2*sn)*sc);
                outp[(long)row*CCH + nb + 16 + col] = (bf16)((x1*sn + x2*cs)*sc);
            }
    } else {
#pragma unroll
        for (int mt = 0; mt < 4; ++mt)
#pragma unroll
            for (int nt = 0; nt < 2; ++nt) {
                int n = nb + nt*16 + col;
                int row0 = mb + mt*16 + quad*4;
                int b = row0 >> 11, sl0 = row0 & (SSQ-1);
                bf16x4 pk;
#pragma unroll
                for (int r = 0; r < 4; ++r) pk[r] = (bf16)acc[mt][nt][r];
                *(bf16x4*)(vout + ((long)(b*CCH + n))*SSQ + sl0) = pk;
            }
    }
}

// ---------------- projection GEMMs
// MODE 3: +bias -> bf16 (B,S,C); MODE 4: +bias+resid -> fp32 (B,C,S) [d_out]
template<int MODE>
__global__ __launch_bounds__(256) void gemm_bf16(const bf16* __restrict__ A,
        const bf16* __restrict__ Wt, const float* __restrict__ bias,
        const float* __restrict__ resid, void* __restrict__ outv) {
    __shared__ char As[2*16384];
    __shared__ char Bs[2*8192];
    int m0 = blockIdx.x*128, n0 = blockIdx.y*64;
    f32x4 acc[4][2] = {};
    gemm_core(A, Wt, m0, n0, As, Bs, acc);
    int tid = threadIdx.x, lane = tid & 63, wid = tid >> 6;
    int sw = wid & 1, nw = wid >> 1;
    int col = lane & 15, quad = lane >> 4;
    int nb = n0 + nw*32, mb = m0 + sw*64;
    if (MODE == 3) {
        bf16* outp = (bf16*)outv;
#pragma unroll
        for (int nt = 0; nt < 2; ++nt) {
            int n = nb + nt*16 + col;
            float bv = bias[n];
#pragma unroll
            for (int mt = 0; mt < 4; ++mt)
#pragma unroll
                for (int r = 0; r < 4; ++r)
                    outp[(long)(mb + mt*16 + quad*4 + r)*CCH + n] = (bf16)(acc[mt][nt][r] + bv);
        }
    } else {
        float* outp = (float*)outv;
#pragma unroll
        for (int mt = 0; mt < 4; ++mt)
#pragma unroll
            for (int nt = 0; nt < 2; ++nt) {
                int n = nb + nt*16 + col;
                float bv = bias[n];
                int row0 = mb + mt*16 + quad*4;
                int b = row0 >> 11, sl0 = row0 & (SSQ-1);
                long off = ((long)(b*CCH + n))*SSQ + sl0;
                float4 rr = *(const float4*)(resid + off);
                float4 o4;
                o4.x = acc[mt][nt][0] + bv + rr.x;
                o4.y = acc[mt][nt][1] + bv + rr.y;
                o4.z = acc[mt][nt][2] + bv + rr.z;
                o4.w = acc[mt][nt][3] + bv + rr.w;
                *(float4*)(outp + off) = o4;
            }
    }
}

// ---------------- MFMA flash attention v5: glds16 double-buffered K/V staging,
// ONE barrier per 64-key tile, linear LDS writes + XOR-swizzled reads,
// fixed-max softmax, precomputed mask multipliers.
// q,k: bf16 (B,S,C); v: bf16 (B,C,S); o: bf16 (B,S,C)
#define KIMG 16384          // per buffer: K 8KB | V^T 8KB
__global__ __launch_bounds__(256) void attn_kernel(
        const bf16* __restrict__ qb, const bf16* __restrict__ kb,
        const bf16* __restrict__ vb, const int* __restrict__ lengths,
        bf16* __restrict__ o) {
    __shared__ char KVs[2][KIMG];
    __shared__ bf16 Ps[4][16*72];
    int b = blockIdx.z, h = blockIdx.y;
    int tid = threadIdx.x, wid = tid >> 6, lane = tid & 63;
    int col = lane & 15, quad = lane >> 4;
    int q0 = blockIdx.x*64 + wid*16;
    int lenb = lengths[b];

    // staging: 1024 chunks of 16B (K 512 | V 512); 4 per thread; linear LDS offsets
    const char* gp[4]; long gstep[4]; int ldsoff[4];
#pragma unroll
    for (int p = 0; p < 4; ++p) {
        int idx = tid + p*256;
        int isV = idx >> 9;
        int rem = idx & 511;
        int r = rem >> 3;
        int csrc = (rem & 7) ^ (r & 7);
        if (!isV) { gp[p] = (const char*)kb + ((long)(b*SSQ + r))*1024 + h*128 + csrc*16; gstep[p] = 65536; }
        else      { gp[p] = (const char*)vb + ((long)(b*CCH + h*64 + r))*4096 + csrc*16;  gstep[p] = 128; }
        ldsoff[p] = idx*16;
    }

    // mask multipliers: valid(key mod 128), period = 2 tiles
    f32x4 vm[2][4];
#pragma unroll
    for (int p2 = 0; p2 < 2; ++p2)
#pragma unroll
        for (int sub = 0; sub < 4; ++sub)
#pragma unroll
            for (int r = 0; r < 4; ++r)
                vm[p2][sub][r] = (p2*64 + sub*16 + quad*4 + r < lenb) ? 1.f : 0.f;

    const bf16* qp = qb + (long)(b*SSQ)*CCH + h*64;
    bf16x8 qf[2];
#pragma unroll
    for (int dc = 0; dc < 2; ++dc)
        qf[dc] = *(const bf16x8*)(qp + (long)(q0 + col)*CCH + dc*32 + quad*8);

    f32x4 of[4] = {};
    float lsum = 0.f;
    bf16* pw = Ps[wid];
    int cswz = col & 7;

    // prologue: stage tile 0 into buf 0
#pragma unroll
    for (int p = 0; p < 4; ++p) glds16(gp[p], KVs[0] + ldsoff[p]);

    for (int t = 0; t < 32; ++t) {
        __syncthreads();                 // drains glds for buf[t&1]
        if (t < 31) {
            char* nbuf = KVs[(t+1) & 1];
#pragma unroll
            for (int p = 0; p < 4; ++p)
                glds16(gp[p] + (long)(t+1)*gstep[p], nbuf + ldsoff[p]);
        }
        const char* K = KVs[t & 1];
        const char* V = KVs[t & 1] + 8192;
        int par = t & 1;
        // ---- S^T = K Q^T
        f32x4 acc[4] = {};
#pragma unroll
        for (int sub = 0; sub < 4; ++sub)
#pragma unroll
            for (int dc = 0; dc < 2; ++dc) {
                bf16x8 kf = *(const bf16x8*)(K + (sub*16 + col)*128 + ((dc*4+quad) ^ cswz)*16);
                acc[sub] = __builtin_amdgcn_mfma_f32_16x16x32_bf16(kf, qf[dc], acc[sub], 0,0,0);
            }
        // ---- exp * mask + lane-local lsum + pack P
#pragma unroll
        for (int sub = 0; sub < 4; ++sub) {
            bf16x4 pk;
#pragma unroll
            for (int r = 0; r < 4; ++r) {
                float p = __expf(acc[sub][r]) * vm[par][sub][r];
                lsum += p;
                pk[r] = (bf16)p;
            }
            *(bf16x4*)(pw + col*72 + sub*16 + quad*4) = pk;
        }
        // ---- O += P V
#pragma unroll
        for (int ks = 0; ks < 2; ++ks) {
            bf16x8 pf = *(const bf16x8*)(pw + col*72 + ks*32 + quad*8);
#pragma unroll
            for (int dt = 0; dt < 4; ++dt) {
                bf16x8 vf = *(const bf16x8*)(V + (dt*16 + col)*128 + ((ks*4+quad) ^ cswz)*16);
                of[dt] = __builtin_amdgcn_mfma_f32_16x16x32_bf16(pf, vf, of[dt], 0,0,0);
            }
        }
    }
    lsum += __shfl_xor(lsum, 16);
    lsum += __shfl_xor(lsum, 32);
    float invl = 1.f / lsum;
    float ir[4];
#pragma unroll
    for (int r = 0; r < 4; ++r) ir[r] = __shfl(invl, quad*4 + r);
    bf16* ob = o + (long)(b*SSQ + q0)*CCH + h*64;
#pragma unroll
    for (int dt = 0; dt < 4; ++dt)
#pragma unroll
        for (int r = 0; r < 4; ++r)
            ob[(long)(quad*4 + r)*CCH + dt*16 + col] = (bf16)(of[dt][r] * ir[r]);
}

extern "C" void kernel_launch(void* const* d_in, const int* in_sizes, int n_in,
                              void* d_out, int out_size, void* d_ws, size_t ws_size,
                              hipStream_t stream) {
    const float* x        = (const float*)d_in[0];
    const int*   lengths  = (const int*)  d_in[1];
    const float* gn_scale = (const float*)d_in[2];
    const float* gn_bias  = (const float*)d_in[3];
    const float* dw_q     = (const float*)d_in[4];
    const float* dw_k     = (const float*)d_in[5];
    const float* dw_v     = (const float*)d_in[6];
    const float* pw_q     = (const float*)d_in[7];
    const float* pw_k     = (const float*)d_in[8];
    const float* pw_v     = (const float*)d_in[9];
    const float* attn_w   = (const float*)d_in[10];
    const float* attn_b   = (const float*)d_in[11];
    const float* out_w    = (const float*)d_in[12];
    const float* out_b    = (const float*)d_in[13];
    float* out = (float*)d_out;

    char* w = (char*)d_ws;
    float* mu   = (float*)w;
    float* rstd = (float*)(w + 1024);
    bf16* wT    = (bf16*)(w + 4096);          // 5 * 512KB
    bf16* wTa = wT + 3*CCH*CCH;
    bf16* wTo = wT + 4*CCH*CCH;
    bf16* xnT  = (bf16*)(w + 0x00300000);
    bf16* yT   = (bf16*)(w + 0x00700000);     // yq|yk|yv contiguous, 4MB each
    bf16* qbf  = (bf16*)(w + 0x01300000);
    bf16* kbf  = (bf16*)(w + 0x01700000);
    bf16* vbf  = (bf16*)(w + 0x01B00000);
    bf16* obf  = (bf16*)(w + 0x01F00000);
    bf16* tmpb = (bf16*)(w + 0x02300000);

    gnw_kernel<<<576, 256, 0, stream>>>(x, mu, rstd, pw_q, pw_k, pw_v, attn_w, out_w, wT);
    tn_kernel<<<dim3(32,8,2), 256, 0, stream>>>(x, mu, rstd, gn_scale, gn_bias, xnT);
    dw3_kernel<<<MTOT/4, 256, 0, stream>>>(xnT, dw_q, dw_k, dw_v,
                                           yT, yT + (long)MTOT*CCH, yT + (long)2*MTOT*CCH);

    gemm_qkv<<<dim3(MTOT/128, CCH/64, 3), 256, 0, stream>>>(yT, wT, qbf, kbf, vbf);

    attn_kernel<<<dim3(SSQ/64, 8, 2), 256, 0, stream>>>(qbf, kbf, vbf, lengths, obf);

    dim3 gg(MTOT/128, CCH/64);
    gemm_bf16<3><<<gg, 256, 0, stream>>>(obf, wTa, attn_b, nullptr, tmpb);
    gemm_bf16<4><<<gg, 256, 0, stream>>>(tmpb, wTo, out_b, x, out);
}

// Round 10
// 172.219 us; speedup vs baseline: 1.0174x; 1.0174x over previous
//
#include <hip/hip_runtime.h>
#include <math.h>

#define CCH 512
#define SSQ 2048           // M*T
#define MTOT 4096          // B*S rows

typedef __bf16 bf16;
typedef __bf16 bf16x8 __attribute__((ext_vector_type(8)));
typedef __bf16 bf16x4 __attribute__((ext_vector_type(4)));
typedef float  f32x4  __attribute__((ext_vector_type(4)));

#define AS1 __attribute__((address_space(1)))
#define AS3 __attribute__((address_space(3)))
__device__ __forceinline__ void glds16(const void* g, void* l) {
    __builtin_amdgcn_global_load_lds((const AS1 void*)g, (AS3 void*)l, 16, 0, 0);
}

// ---------------- fused GN-stats (blocks 0..255) + weight transpose (blocks 256..575)
__global__ __launch_bounds__(256) void gnw_kernel(const float* __restrict__ x,
        float* __restrict__ mu, float* __restrict__ rstd,
        const float* __restrict__ w0, const float* __restrict__ w1,
        const float* __restrict__ w2, const float* __restrict__ w3,
        const float* __restrict__ w4, bf16* __restrict__ wT) {
    __shared__ float smem[64*65];
    int tid = threadIdx.x;
    if (blockIdx.x < 256) {
        float* s_sum = smem;
        float* s_sq  = smem + 256;
        int bg = blockIdx.x;
        long base = (long)bg * 8192;
        float sum = 0.f, sq = 0.f;
#pragma unroll
        for (int r = 0; r < 32; ++r) {
            float v = x[base + r*256 + tid];
            sum += v; sq += v*v;
        }
        s_sum[tid] = sum; s_sq[tid] = sq;
        __syncthreads();
        for (int off = 128; off > 0; off >>= 1) {
            if (tid < off) { s_sum[tid] += s_sum[tid+off]; s_sq[tid] += s_sq[tid+off]; }
            __syncthreads();
        }
        if (tid == 0) {
            float m = s_sum[0] * (1.f/8192.f);
            float v = s_sq[0]  * (1.f/8192.f) - m*m;
            mu[bg] = m;
            rstd[bg] = rsqrtf(v + 1e-5f);
        }
    } else {
        int bid = blockIdx.x - 256;
        int z = bid >> 6, r2 = bid & 63;
        int k0 = (r2 >> 3)*64, n0 = (r2 & 7)*64;
        const float* srcs[5] = {w0, w1, w2, w3, w4};
        const float* W = srcs[z];
        bf16* D = wT + (long)z * (CCH*CCH);
        float (*t)[65] = (float(*)[65])smem;
        int cI = tid & 63, r4 = tid >> 6;
#pragma unroll
        for (int p = 0; p < 16; ++p) {
            int kr = p*4 + r4;
            t[kr][cI] = W[(long)(k0+kr)*CCH + n0 + cI];
        }
        __syncthreads();
#pragma unroll
        for (int p = 0; p < 16; ++p) {
            int nr = p*4 + r4;
            D[(long)(n0+nr)*CCH + k0 + cI] = (bf16)t[cI][nr];
        }
    }
}

// ---------------- transpose+norm: x (B,C,S) fp32 -> xnT (B,S,C) bf16
__global__ void tn_kernel(const float* __restrict__ x, const float* __restrict__ mu,
                          const float* __restrict__ rstd, const float* __restrict__ gsc,
                          const float* __restrict__ gbs, bf16* __restrict__ xnT) {
    __shared__ float t[64][65];
    int s0 = blockIdx.x*64, c0 = blockIdx.y*64, b = blockIdx.z;
    int tid = threadIdx.x;
    int cI = tid & 63, r4 = tid >> 6;
#pragma unroll
    for (int p = 0; p < 16; ++p) {
        int cr = p*4 + r4;
        t[cr][cI] = x[((long)(b*CCH + c0 + cr))*SSQ + s0 + cI];
    }
    __syncthreads();
#pragma unroll
    for (int p = 0; p < 16; ++p) {
        int sr = p*4 + r4;
        int c = c0 + cI;
        int g = b*128 + (c >> 2);
        float v = (t[cI][sr] - mu[g]) * rstd[g] * gsc[c] + gbs[c];
        xnT[((long)(b*SSQ + s0 + sr))*CCH + c] = (bf16)v;
    }
}

// ---------------- fused depthwise 3x3 (SAME) q/k/v on (B,S,C) bf16
__global__ __launch_bounds__(256) void dw3_kernel(const bf16* __restrict__ xnT,
        const float* __restrict__ dwq, const float* __restrict__ dwk,
        const float* __restrict__ dwv,
        bf16* __restrict__ yq, bf16* __restrict__ yk, bf16* __restrict__ yv) {
    int tid = threadIdx.x;
    int cc = (tid & 63) * 8;
    int s  = blockIdx.x*4 + (tid >> 6);
    int sl = s & (SSQ-1);
    int b  = s >> 11;
    int m = sl >> 7, t = sl & 127;
    float aq[8] = {}, ak[8] = {}, av[8] = {};
#pragma unroll
    for (int di = 0; di < 3; ++di) {
        int m2 = m + di - 1;
        if ((unsigned)m2 >= 16u) continue;
#pragma unroll
        for (int dj = 0; dj < 3; ++dj) {
            int t2 = t + dj - 1;
            if ((unsigned)t2 >= 128u) continue;
            bf16x8 xv = *(const bf16x8*)(xnT + ((long)(b*SSQ + m2*128 + t2))*CCH + cc);
            int wi = (di*3 + dj)*CCH + cc;
#pragma unroll
            for (int i = 0; i < 8; ++i) {
                float xf = (float)xv[i];
                aq[i] += xf * dwq[wi+i];
                ak[i] += xf * dwk[wi+i];
                av[i] += xf * dwv[wi+i];
            }
        }
    }
    bf16x8 oq, ok, ov;
#pragma unroll
    for (int i = 0; i < 8; ++i) { oq[i] = (bf16)aq[i]; ok[i] = (bf16)ak[i]; ov[i] = (bf16)av[i]; }
    long o = (long)s*CCH + cc;
    *(bf16x8*)(yq + o) = oq;
    *(bf16x8*)(yk + o) = ok;
    *(bf16x8*)(yv + o) = ov;
}

// ---------------- GEMM core v4: 64x64 tile, BK=64, glds16 double-buffer,
// ONE barrier per K-iter, 4 waves (2x2), wave = 32m x 32n, 8 MFMA/iter.
__device__ __forceinline__ void gemm_core64(const bf16* __restrict__ A,
        const bf16* __restrict__ Wt, int m0, int n0,
        char* As0, char* Bs0, f32x4 acc[2][2]) {
    int tid = threadIdx.x, lane = tid & 63, wid = tid >> 6;
    int sw = wid & 1, nw = wid >> 1;
    int col = lane & 15, quad = lane >> 4;
    const char* gA[2]; const char* gB[2]; int lo[2];
#pragma unroll
    for (int p = 0; p < 2; ++p) {
        int idx = tid + p*256;
        int row = idx >> 3;
        int c = (idx & 7) ^ (row & 7);
        gA[p] = (const char*)A  + ((long)(m0+row)*CCH + c*8)*2;
        gB[p] = (const char*)Wt + ((long)(n0+row)*CCH + c*8)*2;
        lo[p] = idx*16;
    }
    int rowA = sw*32 + col, rowB = nw*32 + col;
#pragma unroll
    for (int p = 0; p < 2; ++p) { glds16(gA[p], As0 + lo[p]); glds16(gB[p], Bs0 + lo[p]); }
#pragma unroll
    for (int it = 0; it < 8; ++it) {
        __syncthreads();
        if (it < 7) {
            int k2 = (it+1)*128;        // byte offset of next k-slice
            char* An = As0 + ((it+1)&1)*8192;
            char* Bn = Bs0 + ((it+1)&1)*8192;
#pragma unroll
            for (int p = 0; p < 2; ++p) { glds16(gA[p]+k2, An+lo[p]); glds16(gB[p]+k2, Bn+lo[p]); }
        }
        const char* Ab = As0 + (it&1)*8192;
        const char* Bb = Bs0 + (it&1)*8192;
        bf16x8 af[2][2], bfr[2][2];
#pragma unroll
        for (int mt = 0; mt < 2; ++mt) {
            int r = rowA + mt*16;
#pragma unroll
            for (int ks = 0; ks < 2; ++ks) {
                int c = (ks*4 + quad) ^ (r & 7);
                af[mt][ks] = *(const bf16x8*)(Ab + r*128 + c*16);
            }
        }
#pragma unroll
        for (int nt = 0; nt < 2; ++nt) {
            int r = rowB + nt*16;
#pragma unroll
            for (int ks = 0; ks < 2; ++ks) {
                int c = (ks*4 + quad) ^ (r & 7);
                bfr[nt][ks] = *(const bf16x8*)(Bb + r*128 + c*16);
            }
        }
#pragma unroll
        for (int ks = 0; ks < 2; ++ks)
#pragma unroll
            for (int mt = 0; mt < 2; ++mt)
#pragma unroll
                for (int nt = 0; nt < 2; ++nt)
                    acc[mt][nt] = __builtin_amdgcn_mfma_f32_16x16x32_bf16(
                        af[mt][ks], bfr[nt][ks], acc[mt][nt], 0,0,0);
    }
}

// ---------------- fused QKV GEMM: z selects matrix + epilogue
__global__ __launch_bounds__(256) void gemm_qkv(const bf16* __restrict__ Abase,
        const bf16* __restrict__ wT, bf16* __restrict__ qout,
        bf16* __restrict__ kout, bf16* __restrict__ vout) {
    __shared__ char As[2*8192];
    __shared__ char Bs[2*8192];
    int m0 = blockIdx.x*64, n0 = blockIdx.y*64, z = blockIdx.z;
    f32x4 acc[2][2] = {};
    gemm_core64(Abase + (long)z*MTOT*CCH, wT + (long)z*CCH*CCH, m0, n0, As, Bs, acc);
    int tid = threadIdx.x, lane = tid & 63, wid = tid >> 6;
    int sw = wid & 1, nw = wid >> 1;
    int col = lane & 15, quad = lane >> 4;
    int nb = n0 + nw*32, mb = m0 + sw*32;
    if (z < 2) {
        bf16* outp = z ? kout : qout;
        float invf = __expf(-(float)col * 0.5756462732485114f);  // 10000^(-col/16)
        bool tHalf = (nb & 32) != 0;
        const float sc = z ? 1.0f : 0.125f;
#pragma unroll
        for (int st = 0; st < 2; ++st)
#pragma unroll
            for (int r = 0; r < 4; ++r) {
                int row = mb + st*16 + quad*4 + r;
                int sl = row & (SSQ-1);
                float pos = tHalf ? (float)(sl & 127) : (float)(sl >> 7);
                float ang = pos * invf;
                float sn, cs;
                __sincosf(ang, &sn, &cs);
                float x1 = acc[st][0][r], x2 = acc[st][1][r];
                outp[(long)row*CCH + nb + col]      = (bf16)((x1*cs - x2*sn)*sc);
                outp[(long)row*CCH + nb + 16 + col] = (bf16)((x1*sn + x2*cs)*sc);
            }
    } else {
#pragma unroll
        for (int st = 0; st < 2; ++st)
#pragma unroll
            for (int nt = 0; nt < 2; ++nt) {
                int n = nb + nt*16 + col;
                int row0 = mb + st*16 + quad*4;
                int b = row0 >> 11, sl0 = row0 & (SSQ-1);
                bf16x4 pk;
#pragma unroll
                for (int r = 0; r < 4; ++r) pk[r] = (bf16)acc[st][nt][r];
                *(bf16x4*)(vout + ((long)(b*CCH + n))*SSQ + sl0) = pk;
            }
    }
}

// ---------------- projection GEMMs
// MODE 3: +bias -> bf16 (B,S,C); MODE 4: +bias+resid -> fp32 (B,C,S) [d_out]
template<int MODE>
__global__ __launch_bounds__(256) void gemm_bf16(const bf16* __restrict__ A,
        const bf16* __restrict__ Wt, const float* __restrict__ bias,
        const float* __restrict__ resid, void* __restrict__ outv) {
    __shared__ char As[2*8192];
    __shared__ char Bs[2*8192];
    int m0 = blockIdx.x*64, n0 = blockIdx.y*64;
    f32x4 acc[2][2] = {};
    gemm_core64(A, Wt, m0, n0, As, Bs, acc);
    int tid = threadIdx.x, lane = tid & 63, wid = tid >> 6;
    int sw = wid & 1, nw = wid >> 1;
    int col = lane & 15, quad = lane >> 4;
    int nb = n0 + nw*32, mb = m0 + sw*32;
    if (MODE == 3) {
        bf16* outp = (bf16*)outv;
#pragma unroll
        for (int nt = 0; nt < 2; ++nt) {
            int n = nb + nt*16 + col;
            float bv = bias[n];
#pragma unroll
            for (int st = 0; st < 2; ++st)
#pragma unroll
                for (int r = 0; r < 4; ++r)
                    outp[(long)(mb + st*16 + quad*4 + r)*CCH + n] = (bf16)(acc[st][nt][r] + bv);
        }
    } else {
        float* outp = (float*)outv;
#pragma unroll
        for (int st = 0; st < 2; ++st)
#pragma unroll
            for (int nt = 0; nt < 2; ++nt) {
                int n = nb + nt*16 + col;
                float bv = bias[n];
                int row0 = mb + st*16 + quad*4;
                int b = row0 >> 11, sl0 = row0 & (SSQ-1);
                long off = ((long)(b*CCH + n))*SSQ + sl0;
                float4 rr = *(const float4*)(resid + off);
                float4 o4;
                o4.x = acc[st][nt][0] + bv + rr.x;
                o4.y = acc[st][nt][1] + bv + rr.y;
                o4.z = acc[st][nt][2] + bv + rr.z;
                o4.w = acc[st][nt][3] + bv + rr.w;
                *(float4*)(outp + off) = o4;
            }
    }
}

// ---------------- MFMA flash attention v6b: K-split=2 (fixed-max softmax =>
// partials additive), single-buffer LDS staging, *bf16* partial O + fp32 l out.
// Partials land INSIDE the dead yT region (high-water kept at proven 39MB).
__global__ __launch_bounds__(256) void attn_kernel(
        const bf16* __restrict__ qb, const bf16* __restrict__ kb,
        const bf16* __restrict__ vb, const int* __restrict__ lengths,
        bf16* __restrict__ po0, bf16* __restrict__ po1,
        float* __restrict__ pl0, float* __restrict__ pl1) {
    __shared__ char KVs[16384];          // [ K 8KB | V^T 8KB ]
    __shared__ bf16 Ps[4][16*72];
    int b = blockIdx.z, h = blockIdx.y;
    int qblk = blockIdx.x >> 1, sp = blockIdx.x & 1;
    int tid = threadIdx.x, wid = tid >> 6, lane = tid & 63;
    int col = lane & 15, quad = lane >> 4;
    int q0 = qblk*64 + wid*16;
    int lenb = lengths[b];

    // staging: 1024 chunks of 16B (K 512 | V 512); 4/thread; linear LDS offsets
    const char* gp[4]; long gstep[4]; int ldsoff[4];
#pragma unroll
    for (int p = 0; p < 4; ++p) {
        int idx = tid + p*256;
        int isV = idx >> 9;
        int rem = idx & 511;
        int r = rem >> 3;
        int csrc = (rem & 7) ^ (r & 7);
        if (!isV) {
            gp[p] = (const char*)kb + ((long)(b*SSQ + sp*1024 + r))*1024 + h*128 + csrc*16;
            gstep[p] = 65536;
        } else {
            gp[p] = (const char*)vb + ((long)(b*CCH + h*64 + r))*4096 + sp*2048 + csrc*16;
            gstep[p] = 128;
        }
        ldsoff[p] = idx*16;
    }

    // mask multipliers: valid(key mod 128), period = 2 tiles (split base 1024 % 128 == 0)
    f32x4 vm[2][4];
#pragma unroll
    for (int p2 = 0; p2 < 2; ++p2)
#pragma unroll
        for (int sub = 0; sub < 4; ++sub)
#pragma unroll
            for (int r = 0; r < 4; ++r)
                vm[p2][sub][r] = (p2*64 + sub*16 + quad*4 + r < lenb) ? 1.f : 0.f;

    const bf16* qp = qb + (long)(b*SSQ)*CCH + h*64;
    bf16x8 qf[2];
#pragma unroll
    for (int dc = 0; dc < 2; ++dc)
        qf[dc] = *(const bf16x8*)(qp + (long)(q0 + col)*CCH + dc*32 + quad*8);

    f32x4 of[4] = {};
    float lsum = 0.f;
    bf16* pw = Ps[wid];
    int cswz = col & 7;

    bf16x8 sreg[4];
#pragma unroll
    for (int p = 0; p < 4; ++p) sreg[p] = *(const bf16x8*)(gp[p]);

    for (int t = 0; t < 16; ++t) {
        __syncthreads();                 // prior tile reads done
#pragma unroll
        for (int p = 0; p < 4; ++p) *(bf16x8*)(KVs + ldsoff[p]) = sreg[p];
        __syncthreads();
        if (t < 15) {
#pragma unroll
            for (int p = 0; p < 4; ++p)
                sreg[p] = *(const bf16x8*)(gp[p] + (long)(t+1)*gstep[p]);
        }
        const char* K = KVs;
        const char* V = KVs + 8192;
        int par = t & 1;
        // ---- S^T = K Q^T
        f32x4 acc[4] = {};
#pragma unroll
        for (int sub = 0; sub < 4; ++sub)
#pragma unroll
            for (int dc = 0; dc < 2; ++dc) {
                bf16x8 kf = *(const bf16x8*)(K + (sub*16 + col)*128 + ((dc*4+quad) ^ cswz)*16);
                acc[sub] = __builtin_amdgcn_mfma_f32_16x16x32_bf16(kf, qf[dc], acc[sub], 0,0,0);
            }
        // ---- exp * mask + lane-local lsum + pack P
#pragma unroll
        for (int sub = 0; sub < 4; ++sub) {
            bf16x4 pk;
#pragma unroll
            for (int r = 0; r < 4; ++r) {
                float p = __expf(acc[sub][r]) * vm[par][sub][r];
                lsum += p;
                pk[r] = (bf16)p;
            }
            *(bf16x4*)(pw + col*72 + sub*16 + quad*4) = pk;
        }
        // ---- O += P V
#pragma unroll
        for (int ks = 0; ks < 2; ++ks) {
            bf16x8 pf = *(const bf16x8*)(pw + col*72 + ks*32 + quad*8);
#pragma unroll
            for (int dt = 0; dt < 4; ++dt) {
                bf16x8 vf = *(const bf16x8*)(V + (dt*16 + col)*128 + ((ks*4+quad) ^ cswz)*16);
                of[dt] = __builtin_amdgcn_mfma_f32_16x16x32_bf16(pf, vf, of[dt], 0,0,0);
            }
        }
    }
    lsum += __shfl_xor(lsum, 16);
    lsum += __shfl_xor(lsum, 32);
    bf16* po = sp ? po1 : po0;
    float* pl = sp ? pl1 : pl0;
    if (quad == 0) pl[(b*8 + h)*SSQ + q0 + col] = lsum;   // l per q-row (lanes 0..15)
    bf16* ob = po + ((long)(b*SSQ + q0))*CCH + h*64;
#pragma unroll
    for (int dt = 0; dt < 4; ++dt)
#pragma unroll
        for (int r = 0; r < 4; ++r)
            ob[(long)(quad*4 + r)*CCH + dt*16 + col] = (bf16)of[dt][r];
}

// ---------------- combine: o = (O1+O2)/(l1+l2), bf16 partials -> bf16 (B,S,C)
__global__ __launch_bounds__(256) void attn_combine(
        const bf16* __restrict__ po0, const bf16* __restrict__ po1,
        const float* __restrict__ pl0, const float* __restrict__ pl1,
        bf16* __restrict__ o) {
    int idx = blockIdx.x*256 + threadIdx.x;   // chunk of 4 elems, [0, 524288)
    int cc = idx & 127;
    int s  = (idx >> 7) & (SSQ-1);
    int b  = idx >> 18;
    int h  = cc >> 4;
    int li = (b*8 + h)*SSQ + s;
    float inv = 1.f / (pl0[li] + pl1[li]);
    bf16x4 a = ((const bf16x4*)po0)[idx];
    bf16x4 c4 = ((const bf16x4*)po1)[idx];
    bf16x4 r;
#pragma unroll
    for (int i = 0; i < 4; ++i)
        r[i] = (bf16)(((float)a[i] + (float)c4[i]) * inv);
    ((bf16x4*)o)[idx] = r;
}

extern "C" void kernel_launch(void* const* d_in, const int* in_sizes, int n_in,
                              void* d_out, int out_size, void* d_ws, size_t ws_size,
                              hipStream_t stream) {
    const float* x        = (const float*)d_in[0];
    const int*   lengths  = (const int*)  d_in[1];
    const float* gn_scale = (const float*)d_in[2];
    const float* gn_bias  = (const float*)d_in[3];
    const float* dw_q     = (const float*)d_in[4];
    const float* dw_k     = (const float*)d_in[5];
    const float* dw_v     = (const float*)d_in[6];
    const float* pw_q     = (const float*)d_in[7];
    const float* pw_k     = (const float*)d_in[8];
    const float* pw_v     = (const float*)d_in[9];
    const float* attn_w   = (const float*)d_in[10];
    const float* attn_b   = (const float*)d_in[11];
    const float* out_w    = (const float*)d_in[12];
    const float* out_b    = (const float*)d_in[13];
    float* out = (float*)d_out;

    // ---- workspace map — HIGH-WATER 0x02700000 (39MB), the R2–R7-proven envelope:
    // [0x00000000] mu/rstd (4KB)            live: gnw -> tn
    // [0x00001000] wT 5x512KB               live: gnw -> gemms
    // [0x00300000] xnT 4MB                  live: tn -> dw3; then pl0/pl1 (attn -> combine)
    // [0x00700000] yT 12MB                  live: dw3 -> qkv; then po0/po1 bf16 4MB each
    // [0x01300000] qbf  [0x01700000] kbf  [0x01B00000] vbf   live: qkv -> attn
    // [0x01F00000] obf 4MB                  live: combine -> proj1
    // [0x02300000] tmpb 4MB                 live: proj1 -> proj2
    char* w = (char*)d_ws;
    float* mu   = (float*)w;
    float* rstd = (float*)(w + 1024);
    bf16* wT    = (bf16*)(w + 4096);
    bf16* wTa = wT + 3*CCH*CCH;
    bf16* wTo = wT + 4*CCH*CCH;
    bf16* xnT  = (bf16*)(w + 0x00300000);
    bf16* yT   = (bf16*)(w + 0x00700000);
    bf16* qbf  = (bf16*)(w + 0x01300000);
    bf16* kbf  = (bf16*)(w + 0x01700000);
    bf16* vbf  = (bf16*)(w + 0x01B00000);
    bf16* obf  = (bf16*)(w + 0x01F00000);
    bf16* tmpb = (bf16*)(w + 0x02300000);
    bf16*  po0 = (bf16*)(w + 0x00700000);     // over yT[0..4MB)  (dead after qkv)
    bf16*  po1 = (bf16*)(w + 0x00B00000);     // over yT[4..8MB)  (dead after qkv)
    float* pl0 = (float*)(w + 0x00300000);    // over xnT (dead after dw3)
    float* pl1 = (float*)(w + 0x00320000);

    gnw_kernel<<<576, 256, 0, stream>>>(x, mu, rstd, pw_q, pw_k, pw_v, attn_w, out_w, wT);
    tn_kernel<<<dim3(32,8,2), 256, 0, stream>>>(x, mu, rstd, gn_scale, gn_bias, xnT);
    dw3_kernel<<<MTOT/4, 256, 0, stream>>>(xnT, dw_q, dw_k, dw_v,
                                           yT, yT + (long)MTOT*CCH, yT + (long)2*MTOT*CCH);

    gemm_qkv<<<dim3(MTOT/64, CCH/64, 3), 256, 0, stream>>>(yT, wT, qbf, kbf, vbf);

    attn_kernel<<<dim3(64, 8, 2), 256, 0, stream>>>(qbf, kbf, vbf, lengths, po0, po1, pl0, pl1);
    attn_combine<<<2048, 256, 0, stream>>>(po0, po1, pl0, pl1, obf);

    dim3 gg(MTOT/64, CCH/64);
    gemm_bf16<3><<<gg, 256, 0, stream>>>(obf, wTa, attn_b, nullptr, tmpb);
    gemm_bf16<4><<<gg, 256, 0, stream>>>(tmpb, wTo, out_b, x, out);
}